// Round 3
// baseline (517.884 us; speedup 1.0000x reference)
//
#include <hip/hip_runtime.h>

// VQ: B=8, C_IN=1024, T=8192, K=1024, D=8
#define B_   8
#define C_   1024
#define T_   8192
#define K_   1024
#define D_   8
#define CT_  (C_ * T_)            // 8388608
#define BT_  (B_ * T_)            // 65536
#define OUTN_ ((size_t)B_ * CT_)  // 67108864 (output 0 elements)

// ---------------------------------------------------------------------------
// Prologue: wT[c][d] = in_w[d][c]  (contiguous 32 B rows -> s_load)
//           nrm[k]   = 0.5*||cb_k||^2 - in_b . cb_k   (bias folded in)
// ---------------------------------------------------------------------------
__global__ __launch_bounds__(256) void vq_prep(
    const float* __restrict__ in_w, const float* __restrict__ in_b,
    const float* __restrict__ cb, float* __restrict__ wT,
    float* __restrict__ nrm)
{
    const int i = blockIdx.x * 256 + threadIdx.x;
    if (i < C_ * D_) {
        const int d = i >> 10;
        const int c = i & (C_ - 1);
        wT[c * D_ + d] = in_w[i];
    }
    if (i < K_) {
        float s = 0.0f, q = 0.0f;
#pragma unroll
        for (int d = 0; d < D_; ++d) {
            const float w = cb[i * D_ + d];
            s = fmaf(w, w, s);
            q = fmaf(in_b[d], w, q);
        }
        nrm[i] = 0.5f * s - q;
    }
}

// ---------------------------------------------------------------------------
// Kernel 1: encode + argmin -> ids only.  512 thr (8 waves), 128-t tile,
// grid 512.  Half-wave hw = lane>>5 owns chunk cnk = 2*wave+hw, so the 16
// v1 64-channel chunks are computed with BIT-IDENTICAL fmaf chains (float4
// z loads, 16 B/lane; i,u ascending).  Weight / codebook / norm rows are
// loaded for BOTH of the wave's chunks as wave-uniform s_loads and selected
// per-lane with cndmask (no LDS, no vector gathers).  Partials staged in two
// 32 KB rounds (rows tt*8+d, cols cnk*32+lane_in_half -> conflict-free),
// reduced over chunks 0..15 ascending -> enc bitwise equal to v1 -> ids
// bitwise equal to v1 (scan order: slot=cnk ascending, j ascending, strict <).
// LDS 36 KB; val/idx alias the staging buffer (dead after round-2 reduce).
// ---------------------------------------------------------------------------
__global__ __launch_bounds__(512, 4) void vq_enc(
    const float* __restrict__ z, const float* __restrict__ wT,
    const float* __restrict__ nrm, const float* __restrict__ cb,
    float* __restrict__ ids_f)
{
    __shared__ float s_part[16 * 512];   // 32 KB (two staging rounds)
    __shared__ float s_enc[32 * 32];     // 4 KB  enc[row=tt*8+d][t-group]

    float* s_val = s_part;               // [16][128]  (alias, plane dead)
    int*   s_idx = (int*)(s_part + 2048);// [16][128]

    const int tid = threadIdx.x;
    const int wu  = __builtin_amdgcn_readfirstlane(tid >> 6); // wave 0..7
    const int l   = tid & 63;
    const int hw  = l >> 5;              // half-wave select (per-lane!)
    const int lc  = l & 31;              // lane within half: t-group 0..31
    const int blk = blockIdx.x;
    const int b   = blk >> 6;            // 64 t-tiles per b
    const int t0  = (blk & 63) << 7;     // 128-t tile base
    const int cnk = 2 * wu + hw;         // chunk id 0..15 (per-lane)
    const int cA  = (wu << 7);           // wave-uniform base of chunk pair

    // ---- phase A: v1-exact partial over the half-wave's 64-channel chunk ---
    float acc[4][D_];
#pragma unroll
    for (int tt = 0; tt < 4; ++tt)
#pragma unroll
        for (int d = 0; d < D_; ++d) acc[tt][d] = 0.0f;

    const float4* zp =
        (const float4*)(z + (size_t)b * CT_ + (size_t)(cnk << 6) * T_ + t0) + lc;
    for (int i = 0; i < 64; i += 4) {
        float4 zv[4];
#pragma unroll
        for (int u = 0; u < 4; ++u)
            zv[u] = zp[(size_t)(i + u) * (T_ / 4)];
#pragma unroll
        for (int u = 0; u < 4; ++u) {
            const float* w0 = wT + (size_t)(cA + i + u) * D_;       // uniform
            const float* w1 = wT + (size_t)(cA + 64 + i + u) * D_;  // uniform
#pragma unroll
            for (int d = 0; d < D_; ++d) {
                const float wv = hw ? w1[d] : w0[d];   // cndmask select
                acc[0][d] = fmaf(zv[u].x, wv, acc[0][d]);
                acc[1][d] = fmaf(zv[u].y, wv, acc[1][d]);
                acc[2][d] = fmaf(zv[u].z, wv, acc[2][d]);
                acc[3][d] = fmaf(zv[u].w, wv, acc[3][d]);
            }
        }
    }

    // ---- stage + reduce in two rounds (16 chunks ascending == v1 order) ----
#pragma unroll
    for (int r = 0; r < 2; ++r) {
        if (r) __syncthreads();          // protect s_part reuse
#pragma unroll
        for (int tp = 0; tp < 2; ++tp)
#pragma unroll
            for (int d = 0; d < D_; ++d)
                s_part[(tp * D_ + d) * 512 + cnk * 32 + lc] = acc[2 * r + tp][d];
        __syncthreads();
        {
            const int row = tid >> 5, col = tid & 31;   // 512 = 16 rows x 32
            float s = 0.0f;
#pragma unroll
            for (int ww = 0; ww < 16; ++ww)
                s += s_part[row * 512 + ww * 32 + col];
            s_enc[(r * 16 + row) * 32 + col] = s;
        }
    }
    __syncthreads();

    // ---- phase B: argmin; half-wave scans its chunk's 64 codes ----
    float e[4][D_];
#pragma unroll
    for (int tt = 0; tt < 4; ++tt)
#pragma unroll
        for (int d = 0; d < D_; ++d)
            e[tt][d] = s_enc[(tt * D_ + d) * 32 + lc];

    float best[4];
    int   bi[4];
#pragma unroll
    for (int tt = 0; tt < 4; ++tt) { best[tt] = 3.4e38f; bi[tt] = 0; }

    for (int j = 0; j < 64; ++j) {
        const float* c0p = cb + (size_t)(cA + j) * D_;        // uniform
        const float* c1p = cb + (size_t)(cA + 64 + j) * D_;   // uniform
        const float nk = hw ? nrm[cA + 64 + j] : nrm[cA + j]; // s_loads+sel
        const int k = (cnk << 6) + j;
        float cw[D_];
#pragma unroll
        for (int d = 0; d < D_; ++d) cw[d] = hw ? c1p[d] : c0p[d];
#pragma unroll
        for (int tt = 0; tt < 4; ++tt) {
            float s = nk;
#pragma unroll
            for (int d = 0; d < D_; ++d) s = fmaf(-e[tt][d], cw[d], s);
            if (s < best[tt]) { best[tt] = s; bi[tt] = k; }  // first min wins
        }
    }
#pragma unroll
    for (int tt = 0; tt < 4; ++tt) {
        s_val[cnk * 128 + 4 * lc + tt] = best[tt];
        s_idx[cnk * 128 + 4 * lc + tt] = bi[tt];
    }
    __syncthreads();

    // ---- scan 16 slots ascending (== k ascending, v1-exact tie-break) ----
    if (tid < 128) {
        float bv = s_val[tid];
        int   bb = s_idx[tid];
#pragma unroll
        for (int ss = 1; ss < 16; ++ss) {
            const float v = s_val[ss * 128 + tid];
            if (v < bv) { bv = v; bb = s_idx[ss * 128 + tid]; }
        }
        ids_f[blk * 128 + tid] = (float)bb;
    }
}

// ---------------------------------------------------------------------------
// Kernel 2: decode.  Pure streaming writes at float4 width.  Grid 4096 =
// 256 t-groups x 16 c-chunks; 256 thr.  Block gathers its 256 zq rows into
// LDS (stride-9 pad), then each wave writes 16 wave-uniform c-rows (out_w /
// out_b via s_load) as float4 stores (1 KB per wave-instruction).  Per-element
// bias+fmaf(d ascending) chain identical to v1 -> out bitwise equal.
// ---------------------------------------------------------------------------
__global__ __launch_bounds__(256) void vq_dec(
    const float* __restrict__ cb, const float* __restrict__ out_w,
    const float* __restrict__ out_b, const float* __restrict__ ids_f,
    float* __restrict__ out)
{
    __shared__ float s_zq[256 * 9];      // 9.2 KB

    const int tid = threadIdx.x;
    const int blk = blockIdx.x;          // 0..4095
    const int grp = blk >> 4;            // 256-t group 0..255
    const int cc  = blk & 15;            // c-chunk 0..15
    const int b   = grp >> 5;
    const int t0  = (grp & 31) << 8;
    const int c0  = cc << 6;

    {
        const int bb = (int)ids_f[grp * 256 + tid];
        const float4* cp = (const float4*)(cb + (size_t)bb * D_);
        const float4 a = cp[0], q = cp[1];
        float* zr = s_zq + tid * 9;
        zr[0] = a.x; zr[1] = a.y; zr[2] = a.z; zr[3] = a.w;
        zr[4] = q.x; zr[5] = q.y; zr[6] = q.z; zr[7] = q.w;
    }
    __syncthreads();

    const int wu = __builtin_amdgcn_readfirstlane(tid >> 6); // wave 0..3
    const int l  = tid & 63;

    float r4[4][D_];
#pragma unroll
    for (int tt = 0; tt < 4; ++tt)
#pragma unroll
        for (int d = 0; d < D_; ++d)
            r4[tt][d] = s_zq[(4 * l + tt) * 9 + d];

    float4* op = (float4*)(out + (size_t)b * CT_ + (size_t)c0 * T_ + t0) + l;
#pragma unroll 4
    for (int j = 0; j < 16; ++j) {
        const int c = c0 + wu * 16 + j;            // wave-uniform
        const float* wr = out_w + (size_t)c * D_;  // s_load
        const float bias = out_b[c];               // s_load
        float4 o;
        o.x = bias; o.y = bias; o.z = bias; o.w = bias;
#pragma unroll
        for (int d = 0; d < D_; ++d) {
            const float wv = wr[d];
            o.x = fmaf(r4[0][d], wv, o.x);
            o.y = fmaf(r4[1][d], wv, o.y);
            o.z = fmaf(r4[2][d], wv, o.z);
            o.w = fmaf(r4[3][d], wv, o.w);
        }
        op[(size_t)(wu * 16 + j) * (T_ / 4)] = o;
    }
}

extern "C" void kernel_launch(void* const* d_in, const int* in_sizes, int n_in,
                              void* d_out, int out_size, void* d_ws, size_t ws_size,
                              hipStream_t stream) {
    const float* z    = (const float*)d_in[0];
    const float* in_w = (const float*)d_in[1];
    const float* in_b = (const float*)d_in[2];
    const float* cb   = (const float*)d_in[3];
    const float* ow   = (const float*)d_in[4];
    const float* ob   = (const float*)d_in[5];

    float* out   = (float*)d_out;
    float* ids_f = out + OUTN_;      // output 1 (ids as float) follows output 0

    float* wT  = (float*)d_ws;       // 8192 floats
    float* nrm = wT + C_ * D_;       // 1024 floats

    vq_prep<<<32, 256, 0, stream>>>(in_w, in_b, cb, wT, nrm);
    vq_enc<<<512, 512, 0, stream>>>(z, wT, nrm, cb, ids_f);
    vq_dec<<<4096, 256, 0, stream>>>(cb, ow, ob, ids_f, out);
}

// Round 5
// 454.356 us; speedup vs baseline: 1.1398x; 1.1398x over previous
//
#include <hip/hip_runtime.h>

// VQ: B=8, C_IN=1024, T=8192, K=1024, D=8
#define B_   8
#define C_   1024
#define T_   8192
#define K_   1024
#define D_   8
#define CT_  (C_ * T_)            // 8388608
#define BT_  (B_ * T_)            // 65536
#define OUTN_ ((size_t)B_ * CT_)  // 67108864 (output 0 elements)

typedef float v4f __attribute__((ext_vector_type(4)));  // nontemporal-safe

// ---------------------------------------------------------------------------
// Prologue: wT[c][d] = in_w[d][c]  (contiguous 32 B rows -> s_load)
//           nrm[k]   = 0.5*||cb_k||^2 - in_b . cb_k   (bias folded in)
// ---------------------------------------------------------------------------
__global__ __launch_bounds__(256) void vq_prep(
    const float* __restrict__ in_w, const float* __restrict__ in_b,
    const float* __restrict__ cb, float* __restrict__ wT,
    float* __restrict__ nrm)
{
    const int i = blockIdx.x * 256 + threadIdx.x;
    if (i < C_ * D_) {
        const int d = i >> 10;
        const int c = i & (C_ - 1);
        wT[c * D_ + d] = in_w[i];
    }
    if (i < K_) {
        float s = 0.0f, q = 0.0f;
#pragma unroll
        for (int d = 0; d < D_; ++d) {
            const float w = cb[i * D_ + d];
            s = fmaf(w, w, s);
            q = fmaf(in_b[d], w, q);
        }
        nrm[i] = 0.5f * s - q;
    }
}

// ---------------------------------------------------------------------------
// Fused encode + argmin + decode.  v5 = v1 arithmetic (bitwise-identical
// chains: 16 chunks of 64 ascending channels, reduce chunks 0..15 ascending,
// argmin slot=chunk ascending + j ascending + strict <, decode bias+fmaf d
// ascending) with TWO structural changes for occupancy:
//   - LDS 131 KB -> 74 KB: partials staged/reduced in TWO 16-plane rounds
//     through a 16x1025 buffer (stride 1025 == 1 mod 32 -> conflict-free).
//   - VGPR capped at 64 via __launch_bounds__(1024, 8): phase A uses only
//     acc(32) + 2 loads in flight(8) + addressing.
// Result: 2 blocks/CU, 32 waves/CU (100%), so one block's mid-phases and
// barriers overlap the other block's HBM streaming.
// Decode uses nontemporal float4 stores (ext_vector_type alias): out is never
// re-read, and skipping write-allocate keeps z LLC-resident (z = 256 MiB).
// ---------------------------------------------------------------------------
__global__ __launch_bounds__(1024, 8) void vq_fused(
    const float* __restrict__ z, const float* __restrict__ wT,
    const float* __restrict__ nrm, const float* __restrict__ cb,
    const float* __restrict__ out_w, const float* __restrict__ out_b,
    float* __restrict__ out, float* __restrict__ ids_f)
{
    __shared__ float s_part[16 * 1025];   // 65.6 KB staging (two rounds)
    __shared__ float s_enc[32 * 64];      // 8 KB  enc[row=tt*8+d][t-group]

    float* s_val = s_part;                // [16][256]  (alias, plane dead)
    int*   s_idx = (int*)(s_part + 4096); // [16][256]
    float* s_zq  = s_part + 8192;         // [256] stride-9 rows (9 KB)

    const int tid = threadIdx.x;
    const int wu  = __builtin_amdgcn_readfirstlane(tid >> 6); // wave 0..15
    const int l   = tid & 63;
    const int blk = blockIdx.x;
    const int b   = blk >> 5;                 // 32 t-tiles per b
    const int t0  = (blk & 31) << 8;          // 256-t tile base
    const int c0  = wu << 6;                  // wave's 64-c / 64-k chunk base

    // ---- phase A: partial projection, v1-exact chain (i,u ascending) ----
    float acc[4][D_];
#pragma unroll
    for (int tt = 0; tt < 4; ++tt)
#pragma unroll
        for (int d = 0; d < D_; ++d) acc[tt][d] = 0.0f;

    const float4* zp =
        (const float4*)(z + (size_t)b * CT_ + (size_t)c0 * T_ + t0) + l;
    for (int i = 0; i < 64; i += 2) {
        float4 zv[2];
#pragma unroll
        for (int u = 0; u < 2; ++u)
            zv[u] = zp[(size_t)(i + u) * (T_ / 4)];
#pragma unroll
        for (int u = 0; u < 2; ++u) {
            const float* wr = wT + (size_t)(c0 + i + u) * D_;  // uniform
#pragma unroll
            for (int d = 0; d < D_; ++d) {
                const float wv = wr[d];
                acc[0][d] = fmaf(zv[u].x, wv, acc[0][d]);
                acc[1][d] = fmaf(zv[u].y, wv, acc[1][d]);
                acc[2][d] = fmaf(zv[u].z, wv, acc[2][d]);
                acc[3][d] = fmaf(zv[u].w, wv, acc[3][d]);
            }
        }
    }

    // ---- two-round stage + reduce (chunks 0..15 ascending == v1 order) ----
#pragma unroll
    for (int r = 0; r < 2; ++r) {
        if (r) __syncthreads();              // protect s_part reuse
#pragma unroll
        for (int h = 0; h < 2; ++h)          // tt = 2r + h
#pragma unroll
            for (int d = 0; d < D_; ++d)
                s_part[(h * D_ + d) * 1025 + tid] = acc[2 * r + h][d];
        __syncthreads();
        {
            const int q = tid >> 6, l2 = tid & 63;  // plane q, t-group l2
            float s = 0.0f;
#pragma unroll
            for (int ww = 0; ww < 16; ++ww)
                s += s_part[q * 1025 + ww * 64 + l2];
            s_enc[(16 * r + q) * 64 + l2] = s;
        }
    }
    __syncthreads();

    // ---- phase B: argmin over wave's 64-k chunk for lane's 4 t's ----
    float e[4][D_];
#pragma unroll
    for (int tt = 0; tt < 4; ++tt)
#pragma unroll
        for (int d = 0; d < D_; ++d)
            e[tt][d] = s_enc[(tt * D_ + d) * 64 + l];

    float best[4];
    int   bi[4];
#pragma unroll
    for (int tt = 0; tt < 4; ++tt) { best[tt] = 3.4e38f; bi[tt] = 0; }

    for (int j = 0; j < 64; ++j) {
        const int k = c0 + j;
        const float* cr = cb + (size_t)k * D_;   // uniform -> s_load
        const float nk = nrm[k];                 // uniform -> s_load
#pragma unroll
        for (int tt = 0; tt < 4; ++tt) {
            float s = nk;
#pragma unroll
            for (int d = 0; d < D_; ++d) s = fmaf(-e[tt][d], cr[d], s);
            if (s < best[tt]) { best[tt] = s; bi[tt] = k; }  // first min wins
        }
    }
#pragma unroll
    for (int tt = 0; tt < 4; ++tt) {
        s_val[wu * 256 + 4 * l + tt] = best[tt];
        s_idx[wu * 256 + 4 * l + tt] = bi[tt];
    }
    __syncthreads();

    // ---- cross-wave argmin scan (ww ascending == k ascending); zq gather ----
    if (tid < 256) {
        float bv = s_val[tid];
        int   bb = s_idx[tid];
#pragma unroll
        for (int ww = 1; ww < 16; ++ww) {
            const float v = s_val[ww * 256 + tid];
            if (v < bv) { bv = v; bb = s_idx[ww * 256 + tid]; }
        }
        ids_f[blk * 256 + tid] = (float)bb;
        const float4* cp = (const float4*)(cb + (size_t)bb * D_);
        const float4 a = cp[0], q = cp[1];
        float* zr = s_zq + tid * 9;
        zr[0] = a.x; zr[1] = a.y; zr[2] = a.z; zr[3] = a.w;
        zr[4] = q.x; zr[5] = q.y; zr[6] = q.z; zr[7] = q.w;
    }
    __syncthreads();

    // ---- decode: wave writes its 64-c chunk, nontemporal float4 stores ----
    float r4[4][D_];
#pragma unroll
    for (int tt = 0; tt < 4; ++tt)
#pragma unroll
        for (int d = 0; d < D_; ++d)
            r4[tt][d] = s_zq[(4 * l + tt) * 9 + d];

    v4f* op = (v4f*)(out + (size_t)b * CT_ + (size_t)c0 * T_ + t0) + l;
#pragma unroll 4
    for (int j = 0; j < 64; ++j) {
        const int c = c0 + j;
        const float* wr = out_w + (size_t)c * D_;  // uniform -> s_load
        const float bias = out_b[c];               // uniform -> s_load
        v4f o;
        o.x = bias; o.y = bias; o.z = bias; o.w = bias;
#pragma unroll
        for (int d = 0; d < D_; ++d) {
            const float wv = wr[d];
            o.x = fmaf(r4[0][d], wv, o.x);
            o.y = fmaf(r4[1][d], wv, o.y);
            o.z = fmaf(r4[2][d], wv, o.z);
            o.w = fmaf(r4[3][d], wv, o.w);
        }
        __builtin_nontemporal_store(o, op + (size_t)j * (T_ / 4));
    }
}

extern "C" void kernel_launch(void* const* d_in, const int* in_sizes, int n_in,
                              void* d_out, int out_size, void* d_ws, size_t ws_size,
                              hipStream_t stream) {
    const float* z    = (const float*)d_in[0];
    const float* in_w = (const float*)d_in[1];
    const float* in_b = (const float*)d_in[2];
    const float* cb   = (const float*)d_in[3];
    const float* ow   = (const float*)d_in[4];
    const float* ob   = (const float*)d_in[5];

    float* out   = (float*)d_out;
    float* ids_f = out + OUTN_;      // output 1 (ids as float) follows output 0

    float* wT  = (float*)d_ws;       // 8192 floats
    float* nrm = wT + C_ * D_;       // 1024 floats

    vq_prep<<<32, 256, 0, stream>>>(in_w, in_b, cb, wT, nrm);
    vq_fused<<<256, 1024, 0, stream>>>(z, wT, nrm, cb, ow, ob, out, ids_f);
}